// Round 1
// baseline (237.132 us; speedup 1.0000x reference)
//
#include <hip/hip_runtime.h>

#define EMBED 192
#define NPB   64          // nodes per block
#define X_HW  512         // input spatial
#define PGRID 256         // patch grid (256x256)

// ---------------- Kernel A: Wf = conv_w^T (192x12) @ gcn_w (192x192) -> (12,192)
__global__ __launch_bounds__(192) void wf_kernel(
    const float* __restrict__ conv_w,   // (192,3,2,2) viewed as (192,12)
    const float* __restrict__ gcn_w,    // (192,192)
    float* __restrict__ wf)             // (12,192)
{
    const int k  = blockIdx.x;    // 0..11
    const int co = threadIdx.x;   // 0..191
    float s = 0.f;
#pragma unroll 4
    for (int c = 0; c < EMBED; ++c)
        s += conv_w[c * 12 + k] * gcn_w[c * EMBED + co];
    wf[k * EMBED + co] = s;
}

// dinv for batch-0 grid node (ph,pw): deg = 1 + #neighbors (+1 for bug node 254,254)
__device__ __forceinline__ float dinv_b0(int ph, int pw) {
    int deg = 1 + (ph > 0) + (ph < PGRID - 1) + (pw > 0) + (pw < PGRID - 1)
                + ((ph == 254) & (pw == 254));
    return rsqrtf((float)deg);
}

// ---------------- Kernel B: fused gather+aggregate+matvec
__global__ __launch_bounds__(192) void fused_kernel(
    const float* __restrict__ x,     // (4,3,512,512)
    const float* __restrict__ wf,    // (12,192)
    const float* __restrict__ bias,  // (192)
    float* __restrict__ out)         // (4,65536,192)
{
    __shared__ float cp[NPB][13];    // combined patches, padded stride 13
    const int tid   = threadIdx.x;           // 0..191
    const int gbase = blockIdx.x * NPB;      // first global node of block
    const int b     = gbase >> 16;           // batch (blocks never straddle)
    const float* xb0 = x + (size_t)b * 3 * X_HW * X_HW;

    // Phase 1: 768 tasks = 64 nodes x 12 patch slots
#pragma unroll
    for (int it = 0; it < 4; ++it) {
        const int task = it * 192 + tid;     // 0..767
        const int k    = task >> 6;          // 0..11 = ic*4 + kh*2 + kw
        const int nl   = task & 63;
        const int n    = (gbase & 65535) + nl;
        const int ph   = n >> 8, pw = n & 255;
        const int ic   = k >> 2, kh = (k >> 1) & 1, kw = k & 1;
        const float* xp = xb0 + (size_t)ic * (X_HW * X_HW)
                        + (ph * 2 + kh) * X_HW + (pw * 2 + kw);
        float v;
        if (b != 0) {
            v = *xp;                          // self-loop only, norm = 1
        } else {
            const float dn = dinv_b0(ph, pw);
            float acc = dn * dn * (*xp);                       // self loop
            if (ph > 0)         acc += dn * dinv_b0(ph - 1, pw) * xp[-2 * X_HW];
            if (ph < PGRID - 1) acc += dn * dinv_b0(ph + 1, pw) * xp[ 2 * X_HW];
            if (pw > 0)         acc += dn * dinv_b0(ph, pw - 1) * xp[-2];
            if (pw < PGRID - 1) acc += dn * dinv_b0(ph, pw + 1) * xp[ 2];
            if (n == 65278)     // bug edge: extra message from node (255,255)
                acc += dn * dinv_b0(255, 255) * xp[(255 - ph) * 2 * X_HW + (255 - pw) * 2];
            v = acc;
        }
        cp[nl][k] = v;
    }
    __syncthreads();

    // Phase 2: each thread owns channel co=tid; 12-FMA matvec per node
    float wfr[12];
#pragma unroll
    for (int k = 0; k < 12; ++k) wfr[k] = wf[k * EMBED + tid];
    const float bco = bias[tid];
    float* op = out + (size_t)gbase * EMBED + tid;
    for (int nl = 0; nl < NPB; ++nl) {
        float acc = bco;
#pragma unroll
        for (int k = 0; k < 12; ++k) acc += cp[nl][k] * wfr[k];
        op[(size_t)nl * EMBED] = acc;
    }
}

extern "C" void kernel_launch(void* const* d_in, const int* in_sizes, int n_in,
                              void* d_out, int out_size, void* d_ws, size_t ws_size,
                              hipStream_t stream) {
    const float* x      = (const float*)d_in[0];
    const float* conv_w = (const float*)d_in[1];
    const float* gcn_w  = (const float*)d_in[2];
    const float* gcn_b  = (const float*)d_in[3];
    float* out = (float*)d_out;
    float* wf  = (float*)d_ws;   // 12*192 floats = 9216 B

    wf_kernel<<<12, EMBED, 0, stream>>>(conv_w, gcn_w, wf);

    const int n_nodes = 4 * PGRID * PGRID;          // 262144
    fused_kernel<<<n_nodes / NPB, EMBED, 0, stream>>>(x, wf, gcn_b, out);
}

// Round 3
// 224.790 us; speedup vs baseline: 1.0549x; 1.0549x over previous
//
#include <hip/hip_runtime.h>

#define EMBED 192
#define NPB   64          // nodes per block (== wavefront size)
#define X_HW  512
#define HW2   (X_HW*X_HW)

// dinv for batch-0 grid node (ph,pw): deg = 1 + #neighbors (+1 for bug node (254,254))
__device__ __forceinline__ float dinv_b0(int ph, int pw) {
    int deg = 1 + (ph > 0) + (ph < 255) + (pw > 0) + (pw < 255)
                + ((ph == 254) & (pw == 254));
    return rsqrtf((float)deg);
}

__device__ __forceinline__ float readlane_f(float v, int lane) {
    return __int_as_float(__builtin_amdgcn_readlane(__float_as_int(v), lane));
}

// ---------------- Kernel A: Wf[k][co] = sum_c conv_w[c][k] * gcn_w[c][co]
// 2304 outputs, one per thread; 4 independent accumulator chains for ILP.
__global__ __launch_bounds__(256) void wf_kernel(
    const float* __restrict__ conv_w,   // (192,12)
    const float* __restrict__ gcn_w,    // (192,192)
    float* __restrict__ wf)             // (12,192)
{
    const int idx = blockIdx.x * 256 + threadIdx.x;   // 0..2303
    const int k   = idx / EMBED;                      // 0..11
    const int co  = idx - k * EMBED;                  // 0..191
    float a0 = 0.f, a1 = 0.f, a2 = 0.f, a3 = 0.f;
#pragma unroll 4
    for (int c = 0; c < EMBED; c += 4) {
        a0 = fmaf(conv_w[(c+0)*12 + k], gcn_w[(c+0)*EMBED + co], a0);
        a1 = fmaf(conv_w[(c+1)*12 + k], gcn_w[(c+1)*EMBED + co], a1);
        a2 = fmaf(conv_w[(c+2)*12 + k], gcn_w[(c+2)*EMBED + co], a2);
        a3 = fmaf(conv_w[(c+3)*12 + k], gcn_w[(c+3)*EMBED + co], a3);
    }
    wf[idx] = (a0 + a1) + (a2 + a3);
}

// ---------------- Kernel B: fused gather+aggregate+matvec, NO LDS.
// Each wave: lane nl holds the combined patch cp[12] of node gbase+nl in VGPRs.
// Mat-vec broadcasts cp across the wave via v_readlane (VALU, not DS pipe).
__global__ __launch_bounds__(192) void fused_kernel(
    const float* __restrict__ x,     // (4,3,512,512)
    const float* __restrict__ wf,    // (12,192)
    const float* __restrict__ bias,  // (192)
    float* __restrict__ out)         // (4,65536,192)
{
    const int tid   = threadIdx.x;           // 0..191
    const int lane  = tid & 63;
    const int gbase = blockIdx.x * NPB;
    const int b     = gbase >> 16;           // batch (blocks never straddle)
    const int n     = (gbase & 65535) + lane;
    const int ph    = n >> 8, pw = n & 255;
    const float* xp0 = x + (size_t)b * 3 * HW2 + (ph * 2) * X_HW + pw * 2;

    float cp[12];
    if (b != 0) {
        // self-loop only (deg=1, norm=1): cp = raw patch
#pragma unroll
        for (int ic = 0; ic < 3; ++ic)
#pragma unroll
            for (int kh = 0; kh < 2; ++kh) {
                const float2 s = *(const float2*)(xp0 + ic * HW2 + kh * X_HW);
                cp[ic*4 + kh*2 + 0] = s.x;
                cp[ic*4 + kh*2 + 1] = s.y;
            }
    } else {
        const float dn  = dinv_b0(ph, pw);
        const float wsf = dn * dn;                                   // self loop
        const float wu  = (ph > 0)   ? dn * dinv_b0(ph-1, pw) : 0.f;
        const float wd  = (ph < 255) ? dn * dinv_b0(ph+1, pw) : 0.f;
        const float wl  = (pw > 0)   ? dn * dinv_b0(ph, pw-1) : 0.f;
        const float wr  = (pw < 255) ? dn * dinv_b0(ph, pw+1) : 0.f;
        // bug edge: node (254,254) receives from (255,255), dinv(255,255)=rsqrt(3)
        const float wb  = (n == 65278) ? dn * 0.5773502691896258f : 0.f;
        // clamped offsets: weight-0 neighbors read a valid (self) address instead
        const int du = (ph > 0)   ? -2 * X_HW : 0;
        const int dd = (ph < 255) ?  2 * X_HW : 0;
        const int dl = (pw > 0)   ? -2 : 0;
        const int dr = (pw < 255) ?  2 : 0;
        const int db = (255 - ph) * 2 * X_HW + (255 - pw) * 2;  // always in-bounds
#pragma unroll
        for (int ic = 0; ic < 3; ++ic)
#pragma unroll
            for (int kh = 0; kh < 2; ++kh) {
                const float* p = xp0 + ic * HW2 + kh * X_HW;
                const float2 s  = *(const float2*)(p);
                const float2 u  = *(const float2*)(p + du);
                const float2 d  = *(const float2*)(p + dd);
                const float2 l  = *(const float2*)(p + dl);
                const float2 r  = *(const float2*)(p + dr);
                const float2 bg = *(const float2*)(p + db);
                cp[ic*4+kh*2+0] = wsf*s.x + wu*u.x + wd*d.x + wl*l.x + wr*r.x + wb*bg.x;
                cp[ic*4+kh*2+1] = wsf*s.y + wu*u.y + wd*d.y + wl*l.y + wr*r.y + wb*bg.y;
            }
    }

    // mat-vec: thread owns channel co=tid; cp broadcast via readlane (no DS pipe)
    float wfr[12];
#pragma unroll
    for (int k = 0; k < 12; ++k) wfr[k] = wf[k * EMBED + tid];
    const float bco = bias[tid];

    float* op = out + (size_t)gbase * EMBED + tid;
#pragma unroll
    for (int nl = 0; nl < NPB; ++nl) {
        float acc = bco;
#pragma unroll
        for (int k = 0; k < 12; ++k)
            acc = fmaf(readlane_f(cp[k], nl), wfr[k], acc);
        op[(size_t)nl * EMBED] = acc;
    }
}

extern "C" void kernel_launch(void* const* d_in, const int* in_sizes, int n_in,
                              void* d_out, int out_size, void* d_ws, size_t ws_size,
                              hipStream_t stream) {
    const float* x      = (const float*)d_in[0];
    const float* conv_w = (const float*)d_in[1];
    const float* gcn_w  = (const float*)d_in[2];
    const float* gcn_b  = (const float*)d_in[3];
    float* out = (float*)d_out;
    float* wf  = (float*)d_ws;   // 12*192 floats = 9216 B

    wf_kernel<<<9, 256, 0, stream>>>(conv_w, gcn_w, wf);

    const int n_nodes = 4 * 256 * 256;              // 262144
    fused_kernel<<<n_nodes / NPB, 192, 0, stream>>>(x, wf, gcn_b, out);
}